// Round 1
// baseline (669.009 us; speedup 1.0000x reference)
//
#include <hip/hip_runtime.h>

#define NN 25000
#define EE 400000
#define FIN 128
#define FE 16
#define CH 32
#define SLOPE 0.01f
#define PROJ_BLOCKS 391   // ceil(25000/64)
#define AUX_BLOCKS 32
#define WROW 24                      // WtL row stride in shorts (48B = 16B-multiple)
#define WTP_SHORTS (1024 * WROW + 8) // global image keeps +8 tail (unread now, harmless)
#define EPB 256                      // edges per k_edge block
#define EDGE_BLOCKS ((EE + EPB - 1) / EPB)   // 1563 (last block ragged: 128 edges)

typedef __attribute__((ext_vector_type(8))) short bf16x8;
typedef __attribute__((ext_vector_type(4))) float f32x4;

__device__ __forceinline__ float lrelu(float v) { return fmaxf(v, SLOPE * v); }

__device__ __forceinline__ f32x4 lrelu4(f32x4 v) {
    f32x4 s = v * SLOPE;
#if __has_builtin(__builtin_elementwise_max)
    return __builtin_elementwise_max(v, s);   // v_pk_max_f32
#else
    f32x4 r;
    r[0] = fmaxf(v[0], s[0]); r[1] = fmaxf(v[1], s[1]);
    r[2] = fmaxf(v[2], s[2]); r[3] = fmaxf(v[3], s[3]);
    return r;
#endif
}

// float -> bf16 bits, round-to-nearest-even
__device__ __forceinline__ short f2bf(float f) {
    union { float f; unsigned u; } v; v.f = f;
    unsigned r = (v.u + 0x7fffu + ((v.u >> 16) & 1u)) >> 16;
    return (short)r;
}

// ---------------- Kernel 1: fused prep
// blocks [0, PROJ_BLOCKS): h = leaky(x @ W_in + b_in) via MFMA (64 nodes/block)
// blocks [PROJ, +4): WtP[co][24] = {bf16 W_edge^T row, bias@16, zeros} ; [+4,+32): zero aggr
__global__ void __launch_bounds__(256)
k_pre(const float* __restrict__ x, const float* __restrict__ W_in,
      const float* __restrict__ b_in, const float* __restrict__ W_edge,
      const float* __restrict__ b_edge,
      float* __restrict__ h, float* __restrict__ aggr, short* __restrict__ WtP) {
    __shared__ short Wt1[CH * 136];
    int tid = threadIdx.x;

    if (blockIdx.x >= PROJ_BLOCKS) {
        int ab = blockIdx.x - PROJ_BLOCKS;
        if (ab < 4) {
            int co = ab * 256 + tid;                       // 0..1023
            short row[WROW] __attribute__((aligned(16)));
#pragma unroll
            for (int k = 0; k < 16; k++) row[k] = f2bf(W_edge[k * 1024 + co]);
            row[16] = f2bf(b_edge[co]);
#pragma unroll
            for (int k = 17; k < WROW; k++) row[k] = 0;
            uint4* dstp = (uint4*)(WtP + co * WROW);       // co*48B, 16B-aligned
            dstp[0] = ((uint4*)row)[0]; dstp[1] = ((uint4*)row)[1]; dstp[2] = ((uint4*)row)[2];
            if (ab == 0 && tid < 8) WtP[1024 * WROW + tid] = 0;   // tail pad
        } else {
            int t = (ab - 4) * 256 + tid;
            float4 z = make_float4(0.f, 0.f, 0.f, 0.f);
            for (int i = t; i < NN * CH / 4; i += (AUX_BLOCKS - 4) * 256)
                ((float4*)aggr)[i] = z;
        }
        return;
    }

    // ---- input projection ----
#pragma unroll
    for (int i = 0; i < 16; i++) {
        int id = tid + 256 * i;           // id = k*32 + c
        int k = id >> 5, c = id & 31;
        Wt1[c * 136 + k] = f2bf(W_in[id]);
    }
    __syncthreads();

    int wave = tid >> 6, lane = tid & 63;
    int n16 = lane & 15, quad = lane >> 4;
    int node0 = blockIdx.x * 64 + wave * 16;

    f32x4 D[2];
#pragma unroll
    for (int ch = 0; ch < 2; ch++) {
        float bb = b_in[ch * 16 + n16];
        D[ch] = (f32x4){bb, bb, bb, bb};
    }
    int arow = node0 + n16; if (arow >= NN) arow = NN - 1;
#pragma unroll
    for (int kb = 0; kb < 4; kb++) {
        const float4* xp = (const float4*)(x + (size_t)arow * FIN + kb * 32 + quad * 8);
        float4 xa = xp[0], xb = xp[1];
        bf16x8 A = (bf16x8){f2bf(xa.x), f2bf(xa.y), f2bf(xa.z), f2bf(xa.w),
                            f2bf(xb.x), f2bf(xb.y), f2bf(xb.z), f2bf(xb.w)};
#pragma unroll
        for (int ch = 0; ch < 2; ch++) {
            bf16x8 B = *(const bf16x8*)&Wt1[(ch * 16 + n16) * 136 + kb * 32 + quad * 8];
            D[ch] = __builtin_amdgcn_mfma_f32_16x16x32_bf16(A, B, D[ch], 0, 0, 0);
        }
    }
#pragma unroll
    for (int ch = 0; ch < 2; ch++)
#pragma unroll
        for (int r = 0; r < 4; r++) {
            int nn = node0 + quad * 4 + r;
            if (nn < NN) h[(size_t)nn * CH + ch * 16 + n16] = lrelu(D[ch][r]);
        }
}

// ---------------- Kernel 2: fused edge-NN (MFMA, bias folded in K-pad) + matvec + scatter
// 512 threads / 8 waves / 256 edges per block. LDS = exactly 80 KiB -> 2 blocks/CU
// = 16 waves/CU (50% occupancy cap, was 25%). Per-wave inner loop unchanged (32 edges).
__global__ void __launch_bounds__(512, 4)
k_edge(const short* __restrict__ WtP,    // [1024][24] bf16 image
       const float* __restrict__ ea,     // [EE][16] f32
       const int* __restrict__ src,
       const int* __restrict__ dst,
       const float* __restrict__ h,
       float* __restrict__ aggr) {
    // single block keeps layout deterministic: WtL @0 (49152 B), hsT @49152 (32768 B)
    __shared__ __align__(16) char smem[81920];
    short* WtL = (short*)smem;               // [1024][24] bf16, no tail pad needed
    float* hsT = (float*)(smem + 49152);     // [32][256] f32, hsT[c][e]

    int tid = threadIdx.x;
    int e0 = blockIdx.x * EPB;

    // stage WtL: 3072 uint4 vector copies (49152 B), 6 per thread, exact fit
#pragma unroll
    for (int j = 0; j < 6; j++) {
        int idx = tid + 512 * j;
        ((uint4*)WtL)[idx] = ((const uint4*)WtP)[idx];
    }
    // stage hsT transposed: thread = (edge e=tid>>1, half=tid&1)
    {
        int e = tid >> 1, half = tid & 1;
        int ei = e0 + e; if (ei >= EE) ei = EE - 1;      // ragged last block: clamp
        int s = src[ei];
        const float4* hp = (const float4*)(h + (size_t)s * CH + half * 16);
        float vv[16] __attribute__((aligned(16)));
        *(float4*)&vv[0] = hp[0]; *(float4*)&vv[4] = hp[1];
        *(float4*)&vv[8] = hp[2]; *(float4*)&vv[12] = hp[3];
#pragma unroll
        for (int j = 0; j < 16; j++) hsT[(half * 16 + j) * EPB + e] = vv[j];
    }
    __syncthreads();

    int wave = tid >> 6, lane = tid & 63;
    int n16 = lane & 15, quad = lane >> 4;
    int t0 = wave * 32, t1 = t0 + 16;

    // A fragments: quads 0,1 = ea (f2bf in regs); quad 2 = {1.0, 0...} (bias row); quad 3 = 0
    bf16x8 A0 = (bf16x8){0,0,0,0,0,0,0,0}, A1 = A0;
    if (quad < 2) {
        int i0 = e0 + t0 + n16; if (i0 >= EE) i0 = EE - 1;
        int i1 = e0 + t1 + n16; if (i1 >= EE) i1 = EE - 1;
        const float4* p0 = (const float4*)(ea + (size_t)i0 * FE + quad * 8);
        float4 a = p0[0], b = p0[1];
        A0 = (bf16x8){f2bf(a.x), f2bf(a.y), f2bf(a.z), f2bf(a.w),
                      f2bf(b.x), f2bf(b.y), f2bf(b.z), f2bf(b.w)};
        const float4* p1 = (const float4*)(ea + (size_t)i1 * FE + quad * 8);
        a = p1[0]; b = p1[1];
        A1 = (bf16x8){f2bf(a.x), f2bf(a.y), f2bf(a.z), f2bf(a.w),
                      f2bf(b.x), f2bf(b.y), f2bf(b.z), f2bf(b.w)};
    } else if (quad == 2) {
        A0[0] = (short)0x3F80; A1[0] = (short)0x3F80;   // bf16 1.0 at k=16
    }

    f32x4 m0[2], m1[2];
    m0[0] = (f32x4){0,0,0,0}; m0[1] = m0[0]; m1[0] = m0[0]; m1[1] = m0[0];
    const f32x4 Z = (f32x4){0,0,0,0};

    // quad 3's A is exactly zero -> its B bits are don't-care. Alias it onto quad 0's
    // slot: removes the old 16B tail-pad over-read (keeps LDS at exactly 80 KiB) and
    // makes quad-3 reads same-address broadcasts with quad 0 (conflict-free).
    int qoff = (quad == 3) ? 0 : quad * 8;
    const short* Bbase = WtL + n16 * WROW + qoff;        // + cb*16*WROW (imm)
    const float* h0b = hsT + t0 + quad * 4;              // + c*EPB (imm)
    const float* h1b = hsT + t1 + quad * 4;

#pragma unroll
    for (int c4 = 0; c4 < 8; c4++) {
#pragma unroll
        for (int cc = 0; cc < 4; cc++) {
            int c = c4 * 4 + cc;
            f32x4 hc0 = *(const f32x4*)(h0b + c * EPB);
            f32x4 hc1 = *(const f32x4*)(h1b + c * EPB);
#pragma unroll
            for (int oh = 0; oh < 2; oh++) {
                int cb = c * 2 + oh;
                bf16x8 B = *(const bf16x8*)(Bbase + cb * (16 * WROW));
                f32x4 D0 = __builtin_amdgcn_mfma_f32_16x16x32_bf16(A0, B, Z, 0, 0, 0);
                f32x4 D1 = __builtin_amdgcn_mfma_f32_16x16x32_bf16(A1, B, Z, 0, 0, 0);
                m0[oh] += hc0 * lrelu4(D0);              // v_pk_fma_f32
                m1[oh] += hc1 * lrelu4(D1);
            }
        }
    }

    // scatter: lane holds msg for edges (tX + quad*4 + r), col o = oh*16 + n16
    // guards are uniformly true except in the single ragged last block
#pragma unroll
    for (int r = 0; r < 4; r++) {
        int i0 = e0 + t0 + quad * 4 + r;
        int i1 = e0 + t1 + quad * 4 + r;
        if (i0 < EE) {
            int ed0 = dst[i0];
#pragma unroll
            for (int oh = 0; oh < 2; oh++)
                unsafeAtomicAdd(&aggr[(size_t)ed0 * CH + oh * 16 + n16], m0[oh][r]);
        }
        if (i1 < EE) {
            int ed1 = dst[i1];
#pragma unroll
            for (int oh = 0; oh < 2; oh++)
                unsafeAtomicAdd(&aggr[(size_t)ed1 * CH + oh * 16 + n16], m1[oh][r]);
        }
    }
}

// ---------------- Kernel 3 (MFMA): out = leaky(aggr + h@W_root + b_conv) @ W_out + b_out
// Wave = 16 nodes. A = h rows (K=32 exact). C = aggr + b_conv. 2 MFMAs (o 0..15, 16..31).
__global__ void __launch_bounds__(256)
k_node(const float* __restrict__ aggr,
       const float* __restrict__ h,
       const float* __restrict__ W_root,
       const float* __restrict__ b_conv,
       const float* __restrict__ W_out,
       const float* __restrict__ b_out,
       float* __restrict__ out) {
    __shared__ short WrB[CH * 40];   // W_root^T bf16: [o][c], stride 40 shorts (80B)
    __shared__ float WoS[CH];
    int tid = threadIdx.x;
    if (tid < 128) {
        int o = tid >> 2, c0 = (tid & 3) * 8;
        short tmp[8] __attribute__((aligned(16)));
#pragma unroll
        for (int j = 0; j < 8; j++) tmp[j] = f2bf(W_root[(c0 + j) * CH + o]);
        *(bf16x8*)&WrB[o * 40 + c0] = *(bf16x8*)tmp;
    } else if (tid < 160) {
        WoS[tid - 128] = W_out[tid - 128];
    }
    __syncthreads();

    int wave = tid >> 6, lane = tid & 63;
    int n16 = lane & 15, quad = lane >> 4;
    int node0 = blockIdx.x * 64 + wave * 16;

    // A: row m=n16 of h (clamped), k = quad*8..+7
    int arow = node0 + n16; if (arow >= NN) arow = NN - 1;
    const float4* hp = (const float4*)(h + (size_t)arow * CH + quad * 8);
    float4 ha = hp[0], hb = hp[1];
    bf16x8 A = (bf16x8){f2bf(ha.x), f2bf(ha.y), f2bf(ha.z), f2bf(ha.w),
                        f2bf(hb.x), f2bf(hb.y), f2bf(hb.z), f2bf(hb.w)};
    // C: aggr + b_conv for rows quad*4+r, cols n16 / 16+n16
    float bc0 = b_conv[n16], bc1 = b_conv[16 + n16];
    f32x4 C0, C1;
#pragma unroll
    for (int r = 0; r < 4; r++) {
        int nr = node0 + quad * 4 + r; int cr = (nr < NN) ? nr : NN - 1;
        C0[r] = aggr[(size_t)cr * CH + n16] + bc0;
        C1[r] = aggr[(size_t)cr * CH + 16 + n16] + bc1;
    }
    bf16x8 B0 = *(const bf16x8*)&WrB[n16 * 40 + quad * 8];
    bf16x8 B1 = *(const bf16x8*)&WrB[(16 + n16) * 40 + quad * 8];
    f32x4 D0 = __builtin_amdgcn_mfma_f32_16x16x32_bf16(A, B0, C0, 0, 0, 0);
    f32x4 D1 = __builtin_amdgcn_mfma_f32_16x16x32_bf16(A, B1, C1, 0, 0, 0);

    // p[r] = lrelu(D0[r])*Wo[n16] + lrelu(D1[r])*Wo[16+n16]; reduce over n16
    float w0 = WoS[n16], w1 = WoS[16 + n16];
    f32x4 p;
#pragma unroll
    for (int r = 0; r < 4; r++)
        p[r] = lrelu(D0[r]) * w0 + lrelu(D1[r]) * w1;
#pragma unroll
    for (int mk = 1; mk < 16; mk <<= 1) {
#pragma unroll
        for (int r = 0; r < 4; r++) p[r] += __shfl_xor(p[r], mk, 64);
    }
    if (n16 == 0) {
        float bo = b_out[0];
#pragma unroll
        for (int r = 0; r < 4; r++) {
            int nr = node0 + quad * 4 + r;
            if (nr < NN) out[nr] = p[r] + bo;
        }
    }
}

extern "C" void kernel_launch(void* const* d_in, const int* in_sizes, int n_in,
                              void* d_out, int out_size, void* d_ws, size_t ws_size,
                              hipStream_t stream) {
    const float* x      = (const float*)d_in[0];
    const int*   ei     = (const int*)d_in[1];
    const float* ea     = (const float*)d_in[2];
    const float* W_in   = (const float*)d_in[3];
    const float* b_in   = (const float*)d_in[4];
    const float* W_edge = (const float*)d_in[5];
    const float* b_edge = (const float*)d_in[6];
    const float* W_root = (const float*)d_in[7];
    const float* b_conv = (const float*)d_in[8];
    const float* W_out  = (const float*)d_in[9];
    const float* b_out  = (const float*)d_in[10];
    float* out  = (float*)d_out;
    float* h    = (float*)d_ws;                  // [NN*CH] f32
    float* aggr = h + (size_t)NN * CH;           // [NN*CH] f32
    short* WtP  = (short*)(aggr + (size_t)NN * CH);  // [WTP_SHORTS] bf16 image

    k_pre<<<PROJ_BLOCKS + AUX_BLOCKS, 256, 0, stream>>>(x, W_in, b_in, W_edge, b_edge,
                                                        h, aggr, WtP);
    k_edge<<<EDGE_BLOCKS, 512, 0, stream>>>(WtP, ea, ei, ei + EE, h, aggr);
    k_node<<<PROJ_BLOCKS, 256, 0, stream>>>(aggr, h, W_root, b_conv, W_out, b_out, out);
}

// Round 2
// 335.394 us; speedup vs baseline: 1.9947x; 1.9947x over previous
//
#include <hip/hip_runtime.h>

#define NN 25000
#define EE 400000
#define FIN 128
#define FE 16
#define CH 32
#define SLOPE 0.01f
#define PROJ_BLOCKS 391   // ceil(25000/64)
#define AUX_BLOCKS 32
#define WROW 24                      // WtL row stride in shorts (48B = 16B-multiple)
#define WTP_SHORTS (1024 * WROW + 8) // global image keeps +8 tail (unread now, harmless)
#define EPB 256                      // edges per k_edge block
#define EDGE_BLOCKS ((EE + EPB - 1) / EPB)   // 1563 (last block ragged: 128 edges)

typedef __attribute__((ext_vector_type(8))) short bf16x8;
typedef __attribute__((ext_vector_type(4))) float f32x4;

__device__ __forceinline__ float lrelu(float v) { return fmaxf(v, SLOPE * v); }

__device__ __forceinline__ f32x4 lrelu4(f32x4 v) {
    f32x4 s = v * SLOPE;
#if __has_builtin(__builtin_elementwise_max)
    return __builtin_elementwise_max(v, s);   // v_pk_max_f32
#else
    f32x4 r;
    r[0] = fmaxf(v[0], s[0]); r[1] = fmaxf(v[1], s[1]);
    r[2] = fmaxf(v[2], s[2]); r[3] = fmaxf(v[3], s[3]);
    return r;
#endif
}

// float -> bf16 bits, round-to-nearest-even
__device__ __forceinline__ short f2bf(float f) {
    union { float f; unsigned u; } v; v.f = f;
    unsigned r = (v.u + 0x7fffu + ((v.u >> 16) & 1u)) >> 16;
    return (short)r;
}

// ---------------- Kernel 1: fused prep
// blocks [0, PROJ_BLOCKS): h = leaky(x @ W_in + b_in) via MFMA (64 nodes/block)
// blocks [PROJ, +4): WtP[co][24] = {bf16 W_edge^T row, bias@16, zeros} ; [+4,+32): zero aggr
__global__ void __launch_bounds__(256)
k_pre(const float* __restrict__ x, const float* __restrict__ W_in,
      const float* __restrict__ b_in, const float* __restrict__ W_edge,
      const float* __restrict__ b_edge,
      float* __restrict__ h, float* __restrict__ aggr, short* __restrict__ WtP) {
    __shared__ short Wt1[CH * 136];
    int tid = threadIdx.x;

    if (blockIdx.x >= PROJ_BLOCKS) {
        int ab = blockIdx.x - PROJ_BLOCKS;
        if (ab < 4) {
            int co = ab * 256 + tid;                       // 0..1023
            short row[WROW] __attribute__((aligned(16)));
#pragma unroll
            for (int k = 0; k < 16; k++) row[k] = f2bf(W_edge[k * 1024 + co]);
            row[16] = f2bf(b_edge[co]);
#pragma unroll
            for (int k = 17; k < WROW; k++) row[k] = 0;
            uint4* dstp = (uint4*)(WtP + co * WROW);       // co*48B, 16B-aligned
            dstp[0] = ((uint4*)row)[0]; dstp[1] = ((uint4*)row)[1]; dstp[2] = ((uint4*)row)[2];
            if (ab == 0 && tid < 8) WtP[1024 * WROW + tid] = 0;   // tail pad
        } else {
            int t = (ab - 4) * 256 + tid;
            float4 z = make_float4(0.f, 0.f, 0.f, 0.f);
            for (int i = t; i < NN * CH / 4; i += (AUX_BLOCKS - 4) * 256)
                ((float4*)aggr)[i] = z;
        }
        return;
    }

    // ---- input projection ----
#pragma unroll
    for (int i = 0; i < 16; i++) {
        int id = tid + 256 * i;           // id = k*32 + c
        int k = id >> 5, c = id & 31;
        Wt1[c * 136 + k] = f2bf(W_in[id]);
    }
    __syncthreads();

    int wave = tid >> 6, lane = tid & 63;
    int n16 = lane & 15, quad = lane >> 4;
    int node0 = blockIdx.x * 64 + wave * 16;

    f32x4 D[2];
#pragma unroll
    for (int ch = 0; ch < 2; ch++) {
        float bb = b_in[ch * 16 + n16];
        D[ch] = (f32x4){bb, bb, bb, bb};
    }
    int arow = node0 + n16; if (arow >= NN) arow = NN - 1;
#pragma unroll
    for (int kb = 0; kb < 4; kb++) {
        const float4* xp = (const float4*)(x + (size_t)arow * FIN + kb * 32 + quad * 8);
        float4 xa = xp[0], xb = xp[1];
        bf16x8 A = (bf16x8){f2bf(xa.x), f2bf(xa.y), f2bf(xa.z), f2bf(xa.w),
                            f2bf(xb.x), f2bf(xb.y), f2bf(xb.z), f2bf(xb.w)};
#pragma unroll
        for (int ch = 0; ch < 2; ch++) {
            bf16x8 B = *(const bf16x8*)&Wt1[(ch * 16 + n16) * 136 + kb * 32 + quad * 8];
            D[ch] = __builtin_amdgcn_mfma_f32_16x16x32_bf16(A, B, D[ch], 0, 0, 0);
        }
    }
#pragma unroll
    for (int ch = 0; ch < 2; ch++)
#pragma unroll
        for (int r = 0; r < 4; r++) {
            int nn = node0 + quad * 4 + r;
            if (nn < NN) h[(size_t)nn * CH + ch * 16 + n16] = lrelu(D[ch][r]);
        }
}

// ---------------- Kernel 2: fused edge-NN (MFMA, bias folded in K-pad) + matvec + scatter
// 512 threads / 8 waves / 256 edges per block. LDS = exactly 80 KiB -> 2 blocks/CU
// = 16 waves/CU (50% occupancy cap).
// __launch_bounds__(512, 2): R1's (512,4) made hipcc budget 64 VGPRs (it treats the
// 2nd arg as min BLOCKS/CU: 4 blocks*8 waves = 8 waves/SIMD -> 512/8 = 64) and the
// ~88-reg body spilled ~1.9 GB of scratch to HBM (FETCH 27->647 MB, WRITE 50->1260 MB).
// (512,2) budgets 128 VGPRs under either semantics -> no spill, LDS-limited 2 blocks/CU.
__global__ void __launch_bounds__(512, 2)
k_edge(const short* __restrict__ WtP,    // [1024][24] bf16 image
       const float* __restrict__ ea,     // [EE][16] f32
       const int* __restrict__ src,
       const int* __restrict__ dst,
       const float* __restrict__ h,
       float* __restrict__ aggr) {
    // single block keeps layout deterministic: WtL @0 (49152 B), hsT @49152 (32768 B)
    __shared__ __align__(16) char smem[81920];
    short* WtL = (short*)smem;               // [1024][24] bf16, no tail pad needed
    float* hsT = (float*)(smem + 49152);     // [32][256] f32, hsT[c][e]

    int tid = threadIdx.x;
    int e0 = blockIdx.x * EPB;

    // stage WtL: 3072 uint4 vector copies (49152 B), 6 per thread, exact fit
#pragma unroll
    for (int j = 0; j < 6; j++) {
        int idx = tid + 512 * j;
        ((uint4*)WtL)[idx] = ((const uint4*)WtP)[idx];
    }
    // stage hsT transposed: thread = (edge e=tid>>1, half=tid&1)
    {
        int e = tid >> 1, half = tid & 1;
        int ei = e0 + e; if (ei >= EE) ei = EE - 1;      // ragged last block: clamp
        int s = src[ei];
        const float4* hp = (const float4*)(h + (size_t)s * CH + half * 16);
        float vv[16] __attribute__((aligned(16)));
        *(float4*)&vv[0] = hp[0]; *(float4*)&vv[4] = hp[1];
        *(float4*)&vv[8] = hp[2]; *(float4*)&vv[12] = hp[3];
#pragma unroll
        for (int j = 0; j < 16; j++) hsT[(half * 16 + j) * EPB + e] = vv[j];
    }
    __syncthreads();

    int wave = tid >> 6, lane = tid & 63;
    int n16 = lane & 15, quad = lane >> 4;
    int t0 = wave * 32, t1 = t0 + 16;

    // A fragments: quads 0,1 = ea (f2bf in regs); quad 2 = {1.0, 0...} (bias row); quad 3 = 0
    bf16x8 A0 = (bf16x8){0,0,0,0,0,0,0,0}, A1 = A0;
    if (quad < 2) {
        int i0 = e0 + t0 + n16; if (i0 >= EE) i0 = EE - 1;
        int i1 = e0 + t1 + n16; if (i1 >= EE) i1 = EE - 1;
        const float4* p0 = (const float4*)(ea + (size_t)i0 * FE + quad * 8);
        float4 a = p0[0], b = p0[1];
        A0 = (bf16x8){f2bf(a.x), f2bf(a.y), f2bf(a.z), f2bf(a.w),
                      f2bf(b.x), f2bf(b.y), f2bf(b.z), f2bf(b.w)};
        const float4* p1 = (const float4*)(ea + (size_t)i1 * FE + quad * 8);
        a = p1[0]; b = p1[1];
        A1 = (bf16x8){f2bf(a.x), f2bf(a.y), f2bf(a.z), f2bf(a.w),
                      f2bf(b.x), f2bf(b.y), f2bf(b.z), f2bf(b.w)};
    } else if (quad == 2) {
        A0[0] = (short)0x3F80; A1[0] = (short)0x3F80;   // bf16 1.0 at k=16
    }

    f32x4 m0[2], m1[2];
    m0[0] = (f32x4){0,0,0,0}; m0[1] = m0[0]; m1[0] = m0[0]; m1[1] = m0[0];
    const f32x4 Z = (f32x4){0,0,0,0};

    // quad 3's A is exactly zero -> its B bits are don't-care. Alias it onto quad 0's
    // slot: removes the old 16B tail-pad over-read (keeps LDS at exactly 80 KiB) and
    // makes quad-3 reads same-address broadcasts with quad 0 (conflict-free).
    int qoff = (quad == 3) ? 0 : quad * 8;
    const short* Bbase = WtL + n16 * WROW + qoff;        // + cb*16*WROW (imm)
    const float* h0b = hsT + t0 + quad * 4;              // + c*EPB (imm)
    const float* h1b = hsT + t1 + quad * 4;

#pragma unroll
    for (int c4 = 0; c4 < 8; c4++) {
#pragma unroll
        for (int cc = 0; cc < 4; cc++) {
            int c = c4 * 4 + cc;
            f32x4 hc0 = *(const f32x4*)(h0b + c * EPB);
            f32x4 hc1 = *(const f32x4*)(h1b + c * EPB);
#pragma unroll
            for (int oh = 0; oh < 2; oh++) {
                int cb = c * 2 + oh;
                bf16x8 B = *(const bf16x8*)(Bbase + cb * (16 * WROW));
                f32x4 D0 = __builtin_amdgcn_mfma_f32_16x16x32_bf16(A0, B, Z, 0, 0, 0);
                f32x4 D1 = __builtin_amdgcn_mfma_f32_16x16x32_bf16(A1, B, Z, 0, 0, 0);
                m0[oh] += hc0 * lrelu4(D0);              // v_pk_fma_f32
                m1[oh] += hc1 * lrelu4(D1);
            }
        }
    }

    // scatter: lane holds msg for edges (tX + quad*4 + r), col o = oh*16 + n16
    // guards are uniformly true except in the single ragged last block
#pragma unroll
    for (int r = 0; r < 4; r++) {
        int i0 = e0 + t0 + quad * 4 + r;
        int i1 = e0 + t1 + quad * 4 + r;
        if (i0 < EE) {
            int ed0 = dst[i0];
#pragma unroll
            for (int oh = 0; oh < 2; oh++)
                unsafeAtomicAdd(&aggr[(size_t)ed0 * CH + oh * 16 + n16], m0[oh][r]);
        }
        if (i1 < EE) {
            int ed1 = dst[i1];
#pragma unroll
            for (int oh = 0; oh < 2; oh++)
                unsafeAtomicAdd(&aggr[(size_t)ed1 * CH + oh * 16 + n16], m1[oh][r]);
        }
    }
}

// ---------------- Kernel 3 (MFMA): out = leaky(aggr + h@W_root + b_conv) @ W_out + b_out
// Wave = 16 nodes. A = h rows (K=32 exact). C = aggr + b_conv. 2 MFMAs (o 0..15, 16..31).
__global__ void __launch_bounds__(256)
k_node(const float* __restrict__ aggr,
       const float* __restrict__ h,
       const float* __restrict__ W_root,
       const float* __restrict__ b_conv,
       const float* __restrict__ W_out,
       const float* __restrict__ b_out,
       float* __restrict__ out) {
    __shared__ short WrB[CH * 40];   // W_root^T bf16: [o][c], stride 40 shorts (80B)
    __shared__ float WoS[CH];
    int tid = threadIdx.x;
    if (tid < 128) {
        int o = tid >> 2, c0 = (tid & 3) * 8;
        short tmp[8] __attribute__((aligned(16)));
#pragma unroll
        for (int j = 0; j < 8; j++) tmp[j] = f2bf(W_root[(c0 + j) * CH + o]);
        *(bf16x8*)&WrB[o * 40 + c0] = *(bf16x8*)tmp;
    } else if (tid < 160) {
        WoS[tid - 128] = W_out[tid - 128];
    }
    __syncthreads();

    int wave = tid >> 6, lane = tid & 63;
    int n16 = lane & 15, quad = lane >> 4;
    int node0 = blockIdx.x * 64 + wave * 16;

    // A: row m=n16 of h (clamped), k = quad*8..+7
    int arow = node0 + n16; if (arow >= NN) arow = NN - 1;
    const float4* hp = (const float4*)(h + (size_t)arow * CH + quad * 8);
    float4 ha = hp[0], hb = hp[1];
    bf16x8 A = (bf16x8){f2bf(ha.x), f2bf(ha.y), f2bf(ha.z), f2bf(ha.w),
                        f2bf(hb.x), f2bf(hb.y), f2bf(hb.z), f2bf(hb.w)};
    // C: aggr + b_conv for rows quad*4+r, cols n16 / 16+n16
    float bc0 = b_conv[n16], bc1 = b_conv[16 + n16];
    f32x4 C0, C1;
#pragma unroll
    for (int r = 0; r < 4; r++) {
        int nr = node0 + quad * 4 + r; int cr = (nr < NN) ? nr : NN - 1;
        C0[r] = aggr[(size_t)cr * CH + n16] + bc0;
        C1[r] = aggr[(size_t)cr * CH + 16 + n16] + bc1;
    }
    bf16x8 B0 = *(const bf16x8*)&WrB[n16 * 40 + quad * 8];
    bf16x8 B1 = *(const bf16x8*)&WrB[(16 + n16) * 40 + quad * 8];
    f32x4 D0 = __builtin_amdgcn_mfma_f32_16x16x32_bf16(A, B0, C0, 0, 0, 0);
    f32x4 D1 = __builtin_amdgcn_mfma_f32_16x16x32_bf16(A, B1, C1, 0, 0, 0);

    // p[r] = lrelu(D0[r])*Wo[n16] + lrelu(D1[r])*Wo[16+n16]; reduce over n16
    float w0 = WoS[n16], w1 = WoS[16 + n16];
    f32x4 p;
#pragma unroll
    for (int r = 0; r < 4; r++)
        p[r] = lrelu(D0[r]) * w0 + lrelu(D1[r]) * w1;
#pragma unroll
    for (int mk = 1; mk < 16; mk <<= 1) {
#pragma unroll
        for (int r = 0; r < 4; r++) p[r] += __shfl_xor(p[r], mk, 64);
    }
    if (n16 == 0) {
        float bo = b_out[0];
#pragma unroll
        for (int r = 0; r < 4; r++) {
            int nr = node0 + quad * 4 + r;
            if (nr < NN) out[nr] = p[r] + bo;
        }
    }
}

extern "C" void kernel_launch(void* const* d_in, const int* in_sizes, int n_in,
                              void* d_out, int out_size, void* d_ws, size_t ws_size,
                              hipStream_t stream) {
    const float* x      = (const float*)d_in[0];
    const int*   ei     = (const int*)d_in[1];
    const float* ea     = (const float*)d_in[2];
    const float* W_in   = (const float*)d_in[3];
    const float* b_in   = (const float*)d_in[4];
    const float* W_edge = (const float*)d_in[5];
    const float* b_edge = (const float*)d_in[6];
    const float* W_root = (const float*)d_in[7];
    const float* b_conv = (const float*)d_in[8];
    const float* W_out  = (const float*)d_in[9];
    const float* b_out  = (const float*)d_in[10];
    float* out  = (float*)d_out;
    float* h    = (float*)d_ws;                  // [NN*CH] f32
    float* aggr = h + (size_t)NN * CH;           // [NN*CH] f32
    short* WtP  = (short*)(aggr + (size_t)NN * CH);  // [WTP_SHORTS] bf16 image

    k_pre<<<PROJ_BLOCKS + AUX_BLOCKS, 256, 0, stream>>>(x, W_in, b_in, W_edge, b_edge,
                                                        h, aggr, WtP);
    k_edge<<<EDGE_BLOCKS, 512, 0, stream>>>(WtP, ea, ei, ei + EE, h, aggr);
    k_node<<<PROJ_BLOCKS, 256, 0, stream>>>(aggr, h, W_root, b_conv, W_out, b_out, out);
}

// Round 3
// 163.644 us; speedup vs baseline: 4.0882x; 2.0495x over previous
//
#include <hip/hip_runtime.h>

#define NN 25000
#define EE 400000
#define FIN 128
#define FE 16
#define CH 32
#define SLOPE 0.01f
#define PROJ_BLOCKS 391   // ceil(25000/64)
#define AUX_BLOCKS 32
#define WROW 24                      // WtL row stride in shorts (48B = 3 x 16B slots)
#define WTP_SHORTS (1024 * WROW)     // 24576 shorts = 48KB image (slot-rotated)
#define NTILES (EE / 128)            // 3125 tiles of 128 edges (exact)
#define PBLK 1024                    // persistent k_edge blocks (~3 tiles each)

typedef __attribute__((ext_vector_type(8))) short bf16x8;
typedef __attribute__((ext_vector_type(4))) float f32x4;

__device__ __forceinline__ float lrelu(float v) { return fmaxf(v, SLOPE * v); }

__device__ __forceinline__ f32x4 lrelu4(f32x4 v) {
    f32x4 s = v * SLOPE;
#if __has_builtin(__builtin_elementwise_max)
    return __builtin_elementwise_max(v, s);
#else
    f32x4 r;
    r[0] = fmaxf(v[0], s[0]); r[1] = fmaxf(v[1], s[1]);
    r[2] = fmaxf(v[2], s[2]); r[3] = fmaxf(v[3], s[3]);
    return r;
#endif
}

// float -> bf16 bits, round-to-nearest-even
__device__ __forceinline__ short f2bf(float f) {
    union { float f; unsigned u; } v; v.f = f;
    unsigned r = (v.u + 0x7fffu + ((v.u >> 16) & 1u)) >> 16;
    return (short)r;
}

// ---------------- Kernel 1: fused prep
// blocks [0, PROJ_BLOCKS): h = leaky(x @ W_in + b_in) via MFMA (64 nodes/block)
// blocks [PROJ, +4): WtP row co = {bf16 W_edge^T row, bias@16, zeros} with its three
//   16B slots ROTATED by co%3 (physical slot p holds logical slot (p - co) mod 3).
//   This spreads k_edge's B-fragment ds_read_b128 banks from 8 banks (8-way conflict,
//   3.6M conflict-cycles/dispatch) to ~2-way (free), at zero in-loop cost.
// blocks [+4, +32): zero aggr
__global__ void __launch_bounds__(256)
k_pre(const float* __restrict__ x, const float* __restrict__ W_in,
      const float* __restrict__ b_in, const float* __restrict__ W_edge,
      const float* __restrict__ b_edge,
      float* __restrict__ h, float* __restrict__ aggr, short* __restrict__ WtP) {
    __shared__ short Wt1[CH * 136];
    int tid = threadIdx.x;

    if (blockIdx.x >= PROJ_BLOCKS) {
        int ab = blockIdx.x - PROJ_BLOCKS;
        if (ab < 4) {
            int co = ab * 256 + tid;                       // 0..1023
            short row[WROW] __attribute__((aligned(16)));
#pragma unroll
            for (int k = 0; k < 16; k++) row[k] = f2bf(W_edge[k * 1024 + co]);
            row[16] = f2bf(b_edge[co]);
#pragma unroll
            for (int k = 17; k < WROW; k++) row[k] = 0;
            uint4* dstp = (uint4*)(WtP + co * WROW);       // co*48B, 16B-aligned
            int p0 = co % 3;                               // physical slot of logical slot 0
            int p1 = p0 + 1; if (p1 == 3) p1 = 0;
            int p2 = p1 + 1; if (p2 == 3) p2 = 0;
            dstp[p0] = ((uint4*)row)[0];                   // logical shorts 0..7
            dstp[p1] = ((uint4*)row)[1];                   // logical shorts 8..15
            dstp[p2] = ((uint4*)row)[2];                   // logical shorts 16..23
        } else {
            int t = (ab - 4) * 256 + tid;
            float4 z = make_float4(0.f, 0.f, 0.f, 0.f);
            for (int i = t; i < NN * CH / 4; i += (AUX_BLOCKS - 4) * 256)
                ((float4*)aggr)[i] = z;
        }
        return;
    }

    // ---- input projection ----
#pragma unroll
    for (int i = 0; i < 16; i++) {
        int id = tid + 256 * i;           // id = k*32 + c
        int k = id >> 5, c = id & 31;
        Wt1[c * 136 + k] = f2bf(W_in[id]);
    }
    __syncthreads();

    int wave = tid >> 6, lane = tid & 63;
    int n16 = lane & 15, quad = lane >> 4;
    int node0 = blockIdx.x * 64 + wave * 16;

    f32x4 D[2];
#pragma unroll
    for (int ch = 0; ch < 2; ch++) {
        float bb = b_in[ch * 16 + n16];
        D[ch] = (f32x4){bb, bb, bb, bb};
    }
    int arow = node0 + n16; if (arow >= NN) arow = NN - 1;
#pragma unroll
    for (int kb = 0; kb < 4; kb++) {
        const float4* xp = (const float4*)(x + (size_t)arow * FIN + kb * 32 + quad * 8);
        float4 xa = xp[0], xb = xp[1];
        bf16x8 A = (bf16x8){f2bf(xa.x), f2bf(xa.y), f2bf(xa.z), f2bf(xa.w),
                            f2bf(xb.x), f2bf(xb.y), f2bf(xb.z), f2bf(xb.w)};
#pragma unroll
        for (int ch = 0; ch < 2; ch++) {
            bf16x8 B = *(const bf16x8*)&Wt1[(ch * 16 + n16) * 136 + kb * 32 + quad * 8];
            D[ch] = __builtin_amdgcn_mfma_f32_16x16x32_bf16(A, B, D[ch], 0, 0, 0);
        }
    }
#pragma unroll
    for (int ch = 0; ch < 2; ch++)
#pragma unroll
        for (int r = 0; r < 4; r++) {
            int nn = node0 + quad * 4 + r;
            if (nn < NN) h[(size_t)nn * CH + ch * 16 + n16] = lrelu(D[ch][r]);
        }
}

// ---------------- Kernel 2: persistent fused edge-NN + matvec + scatter
// 256 threads / 4 waves; PBLK=1024 persistent blocks, each loops ~3 tiles of 128 edges.
// WtL (48KB, slot-rotated) staged ONCE per block (was once per 128 edges = 3125x).
// hsT double-buffered 2x[32][128] f32: next tile's src/h/ea/dst loads issue BEFORE the
// current tile's ~3K-cycle compute -> gather latency hidden (async-stage split).
// LDS = 49152 + 32768 = 81920 B exactly -> 2 blocks/CU. One barrier per tile.
// __launch_bounds__(256,2): 256-VGPR budget (proven 88-reg codegen context; R1/R2's
// tighter caps caused catastrophic scratch spills).
__global__ void __launch_bounds__(256, 2)
k_edge(const short* __restrict__ WtP,    // [1024][24] bf16 image, slots rotated by co%3
       const float* __restrict__ ea,     // [EE][16] f32
       const int* __restrict__ src,
       const int* __restrict__ dst,
       const float* __restrict__ h,
       float* __restrict__ aggr) {
    __shared__ short WtL[WTP_SHORTS];        // 49152 B
    __shared__ float hsT[2][CH * 128];       // 2 x 16384 B, hsT[buf][c][e], stride 128

    int tid = threadIdx.x;

    // stage WtL once: 3072 uint4 (48KB), linear copy (rotation pre-baked in image)
#pragma unroll
    for (int j = 0; j < 12; j++) {
        int idx = tid + 256 * j;
        ((uint4*)WtL)[idx] = ((const uint4*)WtP)[idx];
    }

    int eH = tid >> 1, halfH = tid & 1;      // gather role: edge eH (0..127), half
    int wave = tid >> 6, lane = tid & 63;
    int n16 = lane & 15, quad = lane >> 4;
    int t0 = wave * 32, t1 = t0 + 16;

    // B bases: lane (n16,q) needs logical slot s0 of row co = cb*16+n16, stored at
    // physical slot (s0+co)%3 = ((s0+n16)%3 + cb%3)%3. Three bases, picked by the
    // compile-time cb%3 in the unrolled loop. quad 3 (A==0) aliases quad 0 -> broadcast.
    int s0 = (quad == 3) ? 0 : quad;
    int rot = (s0 + n16) % 3;
    const short* Bb[3];
#pragma unroll
    for (int j = 0; j < 3; j++) {
        int p = rot + j; if (p >= 3) p -= 3;
        Bb[j] = WtL + n16 * WROW + p * 8;    // + cb*384 shorts (imm) in loop
    }

    struct PrefT {
        float hv[16];
        float4 e0a, e0b, e1a, e1b;
        int d[8];
    };
    PrefT Pa, Pb;

    auto PREF = [&](int tile, PrefT& P) {
        int base = tile * 128;
        int s = src[base + eH];
        const float4* hp = (const float4*)(h + (size_t)s * CH + halfH * 16);
        float4 v0 = hp[0], v1 = hp[1], v2 = hp[2], v3 = hp[3];
        *(float4*)&P.hv[0] = v0;  *(float4*)&P.hv[4] = v1;
        *(float4*)&P.hv[8] = v2;  *(float4*)&P.hv[12] = v3;
        if (quad < 2) {
            const float4* p0 = (const float4*)(ea + (size_t)(base + t0 + n16) * FE + quad * 8);
            P.e0a = p0[0]; P.e0b = p0[1];
            const float4* p1 = (const float4*)(ea + (size_t)(base + t1 + n16) * FE + quad * 8);
            P.e1a = p1[0]; P.e1b = p1[1];
        }
#pragma unroll
        for (int r = 0; r < 4; r++) {
            P.d[r]     = dst[base + t0 + quad * 4 + r];
            P.d[4 + r] = dst[base + t1 + quad * 4 + r];
        }
    };

    auto WRITE = [&](float* hbuf, PrefT& P) {
        // banks: addr = (halfH*16+j)*128 + eH -> bank = eH%32, 2 lanes/bank = free
        float* hd = hbuf + halfH * (16 * 128) + eH;
#pragma unroll
        for (int j = 0; j < 16; j++) hd[j * 128] = P.hv[j];
    };

    auto COMPUTE = [&](const float* hbuf, PrefT& P) {
        // A: quads 0,1 = ea (f2bf in regs); quad 2 = {1.0,0..} bias row; quad 3 = 0
        bf16x8 A0 = (bf16x8){0,0,0,0,0,0,0,0}, A1 = A0;
        if (quad < 2) {
            A0 = (bf16x8){f2bf(P.e0a.x), f2bf(P.e0a.y), f2bf(P.e0a.z), f2bf(P.e0a.w),
                          f2bf(P.e0b.x), f2bf(P.e0b.y), f2bf(P.e0b.z), f2bf(P.e0b.w)};
            A1 = (bf16x8){f2bf(P.e1a.x), f2bf(P.e1a.y), f2bf(P.e1a.z), f2bf(P.e1a.w),
                          f2bf(P.e1b.x), f2bf(P.e1b.y), f2bf(P.e1b.z), f2bf(P.e1b.w)};
        } else if (quad == 2) {
            A0[0] = (short)0x3F80; A1[0] = (short)0x3F80;   // bf16 1.0 at k=16
        }

        f32x4 m0[2], m1[2];
        m0[0] = (f32x4){0,0,0,0}; m0[1] = m0[0]; m1[0] = m0[0]; m1[1] = m0[0];
        const f32x4 Z = (f32x4){0,0,0,0};
        const float* h0b = hbuf + t0 + quad * 4;             // + c*128 (imm)
        const float* h1b = hbuf + t1 + quad * 4;

#pragma unroll
        for (int c = 0; c < 32; c++) {
            f32x4 hc0 = *(const f32x4*)(h0b + c * 128);      // quad-broadcast, free
            f32x4 hc1 = *(const f32x4*)(h1b + c * 128);
#pragma unroll
            for (int oh = 0; oh < 2; oh++) {
                int cb = c * 2 + oh;
                bf16x8 B = *(const bf16x8*)(Bb[cb % 3] + cb * (16 * WROW));
                f32x4 D0 = __builtin_amdgcn_mfma_f32_16x16x32_bf16(A0, B, Z, 0, 0, 0);
                f32x4 D1 = __builtin_amdgcn_mfma_f32_16x16x32_bf16(A1, B, Z, 0, 0, 0);
                m0[oh] += hc0 * lrelu4(D0);
                m1[oh] += hc1 * lrelu4(D1);
            }
        }

        // scatter: lane holds msg for edges (tX + quad*4 + r), col o = oh*16 + n16
#pragma unroll
        for (int r = 0; r < 4; r++) {
#pragma unroll
            for (int oh = 0; oh < 2; oh++) {
                unsafeAtomicAdd(&aggr[(size_t)P.d[r]     * CH + oh * 16 + n16], m0[oh][r]);
                unsafeAtomicAdd(&aggr[(size_t)P.d[4 + r] * CH + oh * 16 + n16], m1[oh][r]);
            }
        }
    };

    // persistent tile loop, phase-unrolled double buffer (static buffer indices).
    // Race-safety: a wave reaches WRITE(buf) only after the barrier that followed
    // the last WRITE(buf^1), which in turn is after every wave's COMPUTE(buf) of the
    // previous round -> no writer overtakes a reader.
    int tile = blockIdx.x;
    PREF(tile, Pa);
    while (true) {
        WRITE(&hsT[0][0], Pa);
        __syncthreads();
        int nt = tile + PBLK;
        bool more = (nt < NTILES);
        if (more) PREF(nt, Pb);              // loads fly during COMPUTE below
        COMPUTE(&hsT[0][0], Pa);
        if (!more) break;
        tile = nt;

        WRITE(&hsT[1][0], Pb);
        __syncthreads();
        nt = tile + PBLK;
        more = (nt < NTILES);
        if (more) PREF(nt, Pa);
        COMPUTE(&hsT[1][0], Pb);
        if (!more) break;
        tile = nt;
    }
}

// ---------------- Kernel 3 (MFMA): out = leaky(aggr + h@W_root + b_conv) @ W_out + b_out
__global__ void __launch_bounds__(256)
k_node(const float* __restrict__ aggr,
       const float* __restrict__ h,
       const float* __restrict__ W_root,
       const float* __restrict__ b_conv,
       const float* __restrict__ W_out,
       const float* __restrict__ b_out,
       float* __restrict__ out) {
    __shared__ short WrB[CH * 40];   // W_root^T bf16: [o][c], stride 40 shorts (80B)
    __shared__ float WoS[CH];
    int tid = threadIdx.x;
    if (tid < 128) {
        int o = tid >> 2, c0 = (tid & 3) * 8;
        short tmp[8] __attribute__((aligned(16)));
#pragma unroll
        for (int j = 0; j < 8; j++) tmp[j] = f2bf(W_root[(c0 + j) * CH + o]);
        *(bf16x8*)&WrB[o * 40 + c0] = *(bf16x8*)tmp;
    } else if (tid < 160) {
        WoS[tid - 128] = W_out[tid - 128];
    }
    __syncthreads();

    int wave = tid >> 6, lane = tid & 63;
    int n16 = lane & 15, quad = lane >> 4;
    int node0 = blockIdx.x * 64 + wave * 16;

    int arow = node0 + n16; if (arow >= NN) arow = NN - 1;
    const float4* hp = (const float4*)(h + (size_t)arow * CH + quad * 8);
    float4 ha = hp[0], hb = hp[1];
    bf16x8 A = (bf16x8){f2bf(ha.x), f2bf(ha.y), f2bf(ha.z), f2bf(ha.w),
                        f2bf(hb.x), f2bf(hb.y), f2bf(hb.z), f2bf(hb.w)};
    float bc0 = b_conv[n16], bc1 = b_conv[16 + n16];
    f32x4 C0, C1;
#pragma unroll
    for (int r = 0; r < 4; r++) {
        int nr = node0 + quad * 4 + r; int cr = (nr < NN) ? nr : NN - 1;
        C0[r] = aggr[(size_t)cr * CH + n16] + bc0;
        C1[r] = aggr[(size_t)cr * CH + 16 + n16] + bc1;
    }
    bf16x8 B0 = *(const bf16x8*)&WrB[n16 * 40 + quad * 8];
    bf16x8 B1 = *(const bf16x8*)&WrB[(16 + n16) * 40 + quad * 8];
    f32x4 D0 = __builtin_amdgcn_mfma_f32_16x16x32_bf16(A, B0, C0, 0, 0, 0);
    f32x4 D1 = __builtin_amdgcn_mfma_f32_16x16x32_bf16(A, B1, C1, 0, 0, 0);

    float w0 = WoS[n16], w1 = WoS[16 + n16];
    f32x4 p;
#pragma unroll
    for (int r = 0; r < 4; r++)
        p[r] = lrelu(D0[r]) * w0 + lrelu(D1[r]) * w1;
#pragma unroll
    for (int mk = 1; mk < 16; mk <<= 1) {
#pragma unroll
        for (int r = 0; r < 4; r++) p[r] += __shfl_xor(p[r], mk, 64);
    }
    if (n16 == 0) {
        float bo = b_out[0];
#pragma unroll
        for (int r = 0; r < 4; r++) {
            int nr = node0 + quad * 4 + r;
            if (nr < NN) out[nr] = p[r] + bo;
        }
    }
}

extern "C" void kernel_launch(void* const* d_in, const int* in_sizes, int n_in,
                              void* d_out, int out_size, void* d_ws, size_t ws_size,
                              hipStream_t stream) {
    const float* x      = (const float*)d_in[0];
    const int*   ei     = (const int*)d_in[1];
    const float* ea     = (const float*)d_in[2];
    const float* W_in   = (const float*)d_in[3];
    const float* b_in   = (const float*)d_in[4];
    const float* W_edge = (const float*)d_in[5];
    const float* b_edge = (const float*)d_in[6];
    const float* W_root = (const float*)d_in[7];
    const float* b_conv = (const float*)d_in[8];
    const float* W_out  = (const float*)d_in[9];
    const float* b_out  = (const float*)d_in[10];
    float* out  = (float*)d_out;
    float* h    = (float*)d_ws;                  // [NN*CH] f32
    float* aggr = h + (size_t)NN * CH;           // [NN*CH] f32
    short* WtP  = (short*)(aggr + (size_t)NN * CH);  // [WTP_SHORTS] bf16 image

    k_pre<<<PROJ_BLOCKS + AUX_BLOCKS, 256, 0, stream>>>(x, W_in, b_in, W_edge, b_edge,
                                                        h, aggr, WtP);
    k_edge<<<PBLK, 256, 0, stream>>>(WtP, ea, ei, ei + EE, h, aggr);
    k_node<<<PROJ_BLOCKS, 256, 0, stream>>>(aggr, h, W_root, b_conv, W_out, b_out, out);
}